// Round 11
// baseline (454.477 us; speedup 1.0000x reference)
//
#include <hip/hip_runtime.h>
#include <hip/hip_fp16.h>

// ---------------------------------------------------------------------------
// LinkPredModel: 2-layer GraphSAGE (mean aggr) + dot-product link scoring.
// N=100000 nodes, D=H=128, E=3.2M edges, L=200k label pairs.
// Round 11: dispatch-count cut 14 -> 7. (a) prep = cast+repack+hist partials
// (no memset, ILP-parallel sum in bucket_scan — fixes R9's serial-sum bug);
// (b) per-layer fused aggmm: wave aggregates its own 16 rows (R10 inner loop),
// parks them in LDS, then MFMA dual-GEMM (A from LDS, F/W from global).
// Grid ceil(N/64) keeps ~24 waves/CU so agg MLP is preserved.
// ---------------------------------------------------------------------------

#define D128 128
#define BSHIFT 9          // 512 nodes per bucket
#define BNODES 512

typedef __bf16 bf16x8 __attribute__((ext_vector_type(8)));
typedef float  f32x4  __attribute__((ext_vector_type(4)));
typedef _Float16 h2   __attribute__((ext_vector_type(2)));

union uh2cast { unsigned u; h2 h; };
__device__ inline h2 uash2(unsigned u) { uh2cast c; c.u = u; return c.h; }

__device__ inline unsigned short f2bf(float f) {
    unsigned u = __float_as_uint(f);
    u = u + 0x7FFF + ((u >> 16) & 1);   // round-to-nearest-even
    return (unsigned short)(u >> 16);
}
__device__ inline float bf2f(unsigned short s) {
    return __uint_as_float(((unsigned)s) << 16);
}
__device__ inline unsigned packbf2(float lo, float hi) {
    return (unsigned)f2bf(lo) | ((unsigned)f2bf(hi) << 16);
}
// fp8 e5m2 encode. HW packer when available (1 VALU), else fp16 double-round.
__device__ inline unsigned char f2e5(float f) {
#if __has_builtin(__builtin_amdgcn_cvt_pk_bf8_f32)
    return (unsigned char)(__builtin_amdgcn_cvt_pk_bf8_f32(f, f, 0, false) & 0xFF);
#else
    unsigned short h = __half_as_ushort(__float2half(f));  // RNE f32->fp16
    h = (unsigned short)(h + 0x7F + ((h >> 8) & 1));       // RNE fp16->e5m2
    return (unsigned char)(h >> 8);
#endif
}

// ---------------- fused prep: cast | weight repack | bucket hist partials ----

__global__ void prep_kernel(const float* __restrict__ in, unsigned short* __restrict__ outb,
                            unsigned char* __restrict__ out8, int n4,
                            const float* __restrict__ W1l, const float* __restrict__ W1r,
                            const float* __restrict__ W2l, const float* __restrict__ W2r,
                            unsigned short* __restrict__ packed,
                            const int* __restrict__ dst, int* __restrict__ bh,
                            int E, int castBlocks, int histBlocks) {
    int bid = blockIdx.x;
    int t = threadIdx.x;
    if (bid < castBlocks) {
        int i = bid * 256 + t;
        if (i >= n4) return;
        float4 v = ((const float4*)in)[i];
        ushort4 ob;
        ob.x = f2bf(v.x); ob.y = f2bf(v.y); ob.z = f2bf(v.z); ob.w = f2bf(v.w);
        ((ushort4*)outb)[i] = ob;
        unsigned p = (unsigned)f2e5(v.x) | ((unsigned)f2e5(v.y) << 8) |
                     ((unsigned)f2e5(v.z) << 16) | ((unsigned)f2e5(v.w) << 24);
        ((unsigned*)out8)[i] = p;
    } else if (bid < castBlocks + 256) {
        // weight repack: packed[layer][kc][nt][lane][j] = W[k][col],
        // k=kc*32+(lane>>4)*8+j, col=nt*16+(lane&15); k<128 -> Wl else Wr.
        int tid = (bid - castBlocks) * 256 + t;  // [0, 65536)
        int layer = tid >> 15;
        int r = tid & 32767;
        int j    = r & 7;
        int lane = (r >> 3) & 63;
        int nt   = (r >> 9) & 7;
        int kc   = (r >> 12) & 7;
        int k   = kc * 32 + ((lane >> 4) << 3) + j;
        int col = nt * 16 + (lane & 15);
        const float* Wl = layer ? W2l : W1l;
        const float* Wr = layer ? W2r : W1r;
        float v = (k < 128) ? Wl[k * 128 + col] : Wr[(k - 128) * 128 + col];
        packed[tid] = f2bf(v);
    } else {
        // bucket histogram partials (plain stores, no memset/global atomics)
        __shared__ int h[256];
        int hb = bid - castBlocks - 256;
        if (hb >= histBlocks) return;
        h[t] = 0;
        __syncthreads();
        int base = hb * 8192;
#pragma unroll
        for (int k = 0; k < 32; ++k) {
            int e = base + k * 256 + t;
            if (e < E) atomicAdd(&h[dst[e] >> BSHIFT], 1);
        }
        __syncthreads();
        bh[hb * 256 + t] = h[t];
    }
}

// ---------------- bucket scan: ILP-parallel partial-sum + exclusive scan ------

__global__ void bucket_scan(const int* __restrict__ bh, int nhb,
                            int* __restrict__ bucket_base, int* __restrict__ bucket_cur,
                            int* __restrict__ rowptr, int NB, int N, int E) {
    __shared__ int sc[256];
    __shared__ int orig[256];
    int t = threadIdx.x;
    int a0 = 0, a1 = 0, a2 = 0, a3 = 0, a4 = 0, a5 = 0, a6 = 0, a7 = 0;
    int b = 0;
    for (; b + 8 <= nhb; b += 8) {
        a0 += bh[(b + 0) * 256 + t];
        a1 += bh[(b + 1) * 256 + t];
        a2 += bh[(b + 2) * 256 + t];
        a3 += bh[(b + 3) * 256 + t];
        a4 += bh[(b + 4) * 256 + t];
        a5 += bh[(b + 5) * 256 + t];
        a6 += bh[(b + 6) * 256 + t];
        a7 += bh[(b + 7) * 256 + t];
    }
    for (; b < nhb; ++b) a0 += bh[b * 256 + t];
    int v = ((a0 + a1) + (a2 + a3)) + ((a4 + a5) + (a6 + a7));
    if (t >= NB) v = 0;
    orig[t] = v;
    sc[t] = v;
    __syncthreads();
    for (int off = 1; off < 256; off <<= 1) {
        int a = (t >= off) ? sc[t - off] : 0;
        __syncthreads();
        sc[t] += a;
        __syncthreads();
    }
    int ex = sc[t] - orig[t];
    if (t < NB) { bucket_base[t] = ex; bucket_cur[t] = ex; }
    if (t == 0) { bucket_base[NB] = E; rowptr[N] = E; }
}

// packed edge word: (src << 9) | (dst & 511); src < 2^17, so fits in 26 bits.
__global__ void scatter_kernel(const int* __restrict__ src, const int* __restrict__ dst,
                               int* __restrict__ bucket_cur, int* __restrict__ pairs,
                               int E, int NB) {
    __shared__ int hist[256], lscan[256], gbase[256];
    __shared__ int lsrc[1024], ldst[1024];
    int t = threadIdx.x;
    hist[t] = 0;
    __syncthreads();
    int base = blockIdx.x * 1024;
    int total = E - base; if (total > 1024) total = 1024;

    int ms[4], md[4], mb[4], mr[4];
#pragma unroll
    for (int k = 0; k < 4; ++k) {
        int i = k * 256 + t;
        int e = base + i;
        mb[k] = -1;
        if (i < total) {
            ms[k] = src[e];
            md[k] = dst[e];
            mb[k] = md[k] >> BSHIFT;
            mr[k] = atomicAdd(&hist[mb[k]], 1);
        }
    }
    __syncthreads();
    lscan[t] = hist[t];
    __syncthreads();
    for (int off = 1; off < 256; off <<= 1) {
        int a = (t >= off) ? lscan[t - off] : 0;
        __syncthreads();
        lscan[t] += a;
        __syncthreads();
    }
    lscan[t] -= hist[t];
    if (t < NB && hist[t] > 0) gbase[t] = atomicAdd(&bucket_cur[t], hist[t]);
    __syncthreads();
#pragma unroll
    for (int k = 0; k < 4; ++k) {
        if (mb[k] >= 0) {
            int idx = lscan[mb[k]] + mr[k];
            lsrc[idx] = ms[k];
            ldst[idx] = md[k];
        }
    }
    __syncthreads();
#pragma unroll
    for (int k = 0; k < 4; ++k) {
        int i = k * 256 + t;
        if (i < total) {
            int d = ldst[i];
            int b = d >> BSHIFT;
            int pos = gbase[b] + (i - lscan[b]);
            pairs[pos] = (lsrc[i] << BSHIFT) | (d & (BNODES - 1));
        }
    }
}

// srcs stores PRE-SCALED row index: src*16 (uint2 units for a 128B fp8 row).
__global__ void bucket_fill(const int* __restrict__ pairs, const int* __restrict__ bucket_base,
                            int* __restrict__ rowptr, int* __restrict__ srcs, int N) {
    __shared__ int hist[BNODES], excl[BNODES], sc[BNODES];
    int b = blockIdx.x;
    int t = threadIdx.x;      // blockDim = 512
    int node0 = b << BSHIFT;
    int pbeg = bucket_base[b];
    int pend = bucket_base[b + 1];
    hist[t] = 0;
    __syncthreads();
    for (int p = pbeg + t; p < pend; p += BNODES) {
        atomicAdd(&hist[pairs[p] & (BNODES - 1)], 1);
    }
    __syncthreads();
    sc[t] = hist[t];
    __syncthreads();
    for (int off = 1; off < BNODES; off <<= 1) {
        int a = (t >= off) ? sc[t - off] : 0;
        __syncthreads();
        sc[t] += a;
        __syncthreads();
    }
    excl[t] = sc[t] - hist[t];
    int node = node0 + t;
    if (node < N) rowptr[node] = pbeg + excl[t];
    __syncthreads();
    hist[t] = 0;
    __syncthreads();
    for (int p = pbeg + t; p < pend; p += BNODES) {
        int w = pairs[p];
        int dl = w & (BNODES - 1);
        int c = atomicAdd(&hist[dl], 1);
        srcs[pbeg + excl[dl] + c] = (int)(((unsigned)w) >> BSHIFT) << 4;
    }
}

// ---------------- fused agg + MFMA dual-GEMM (one layer) ----------------
// Wave owns 16 rows: phase 1 aggregates them (R10 inner loop, fp8 gather,
// pk_add_f16) into LDS (bf16); phase 2 computes out = act([agg|F]@Wp + b)
// with A-fragments from LDS, F/W from global. 64 rows per 256-thread block.

__device__ inline void pkacc8(h2* A, uint2 v) {
    A[0] += uash2((v.x << 8) & 0xFF00FF00u);   // cols 0,2
    A[1] += uash2(v.x & 0xFF00FF00u);          // cols 1,3
    A[2] += uash2((v.y << 8) & 0xFF00FF00u);   // cols 4,6
    A[3] += uash2(v.y & 0xFF00FF00u);          // cols 5,7
}

template <bool LEAKY>
__global__ void aggmm_kernel(const int* __restrict__ rowptr, const int* __restrict__ srcs,
                             const unsigned char* __restrict__ feat8,
                             const unsigned short* __restrict__ F,
                             const unsigned short* __restrict__ Wp,
                             const float* __restrict__ bias,
                             unsigned short* __restrict__ out,
                             unsigned char* __restrict__ out8, int N) {
    __shared__ unsigned short ldsA[4 * 16 * D128];   // 16 KB: 4 waves x 16 rows
    int wid = threadIdx.x >> 6;
    int lane = threadIdx.x & 63;
    int q  = lane >> 4;    // quarter
    int ql = lane & 15;
    int m0 = (blockIdx.x * 4 + wid) * 16;
    const uint2* f = (const uint2*)feat8;   // 16 uint2 per 128B fp8 row

    // ---- phase 1: aggregate rows m0..m0+15 into LDS ----
    for (int r = 0; r < 16; ++r) {
        int n = m0 + r;
        if (n >= N) break;
        int beg = rowptr[n];
        int end = rowptr[n + 1];

        h2 A0[4], A1[4], A2[4], A3[4];
        h2 z; z[0] = (_Float16)0.f; z[1] = (_Float16)0.f;
#pragma unroll
        for (int k = 0; k < 4; ++k) { A0[k] = z; A1[k] = z; A2[k] = z; A3[k] = z; }

        int j = beg;
        for (; j + 16 <= end; j += 16) {
            int e0 = srcs[j + q];
            int e1 = srcs[j + 4 + q];
            int e2 = srcs[j + 8 + q];
            int e3 = srcs[j + 12 + q];
            uint2 v0 = f[e0 + ql];
            uint2 v1 = f[e1 + ql];
            uint2 v2 = f[e2 + ql];
            uint2 v3 = f[e3 + ql];
            pkacc8(A0, v0);
            pkacc8(A1, v1);
            pkacc8(A2, v2);
            pkacc8(A3, v3);
        }
        for (; j + 4 <= end; j += 4) {
            uint2 v = f[srcs[j + q] + ql];
            pkacc8(A0, v);
        }
        int rem = end - j;
        if (q < rem) {
            uint2 v = f[srcs[j + q] + ql];
            pkacc8(A1, v);
        }

        float c[8];
#pragma unroll
        for (int p = 0; p < 4; ++p) {
            float lo = (float)A0[p][0] + (float)A1[p][0] + (float)A2[p][0] + (float)A3[p][0];
            float hi = (float)A0[p][1] + (float)A1[p][1] + (float)A2[p][1] + (float)A3[p][1];
            int base = (p >> 1) * 4 + (p & 1);
            c[base] = lo;
            c[base + 2] = hi;
        }
#pragma unroll
        for (int k = 0; k < 8; ++k) {
            c[k] += __shfl_xor(c[k], 16, 64);
            c[k] += __shfl_xor(c[k], 32, 64);
        }
        int deg = end - beg;
        float inv = deg > 0 ? 1.0f / (float)deg : 0.f;
        if (q == 0) {
            uint4 rr;
            rr.x = packbf2(c[0] * inv, c[1] * inv);
            rr.y = packbf2(c[2] * inv, c[3] * inv);
            rr.z = packbf2(c[4] * inv, c[5] * inv);
            rr.w = packbf2(c[6] * inv, c[7] * inv);
            ((uint4*)ldsA)[wid * 256 + r * 16 + ql] = rr;   // row r, cols ql*8..+7
        }
    }
    __syncthreads();

    // ---- phase 2: 16-row MFMA dual-GEMM ----
    int rl = lane & 15;
    int rowF = m0 + rl;
    if (rowF > N - 1) rowF = N - 1;
    const unsigned short* ldsW = ldsA + wid * 16 * D128;

    f32x4 acc[8];
#pragma unroll
    for (int nt = 0; nt < 8; ++nt) acc[nt] = (f32x4){0.f, 0.f, 0.f, 0.f};

#pragma unroll
    for (int kc = 0; kc < 8; ++kc) {
        bf16x8 af;
        if (kc < 4) af = *(const bf16x8*)(ldsW + rl * D128 + kc * 32 + q * 8);
        else        af = *(const bf16x8*)(F + (size_t)rowF * D128 + (kc - 4) * 32 + q * 8);
        const unsigned short* wp = Wp + ((size_t)kc * 8) * 512 + lane * 8;
#pragma unroll
        for (int nt = 0; nt < 8; ++nt) {
            bf16x8 bf = *(const bf16x8*)(wp + nt * 512);
            acc[nt] = __builtin_amdgcn_mfma_f32_16x16x32_bf16(af, bf, acc[nt], 0, 0, 0);
        }
    }

#pragma unroll
    for (int nt = 0; nt < 8; ++nt) {
        int col = nt * 16 + rl;
        float bv = bias[col];
#pragma unroll
        for (int r = 0; r < 4; ++r) {
            int row = m0 + q * 4 + r;
            if (row < N) {
                float v = acc[nt][r] + bv;
                if (LEAKY) v = v >= 0.f ? v : 0.2f * v;
                out[(size_t)row * D128 + col] = f2bf(v);
                if (out8) out8[(size_t)row * D128 + col] = f2e5(v);
            }
        }
    }
}

// ---------------- link scoring: 4 pairs per wave (8 gathers in flight) ----------------

__global__ void score_kernel(const int* __restrict__ eli, const unsigned short* __restrict__ h,
                             float* __restrict__ out, int L) {
    int wave = threadIdx.x >> 6;
    int lane = threadIdx.x & 63;
    int l0 = (blockIdx.x * 4 + wave) * 4;
    if (l0 >= L) return;
    const ushort2* h2p = (const ushort2*)h;
    int a[4], b[4];
#pragma unroll
    for (int k = 0; k < 4; ++k) {
        int l = l0 + k;
        if (l > L - 1) l = L - 1;
        a[k] = eli[l];
        b[k] = eli[L + l];
    }
    float p[4];
#pragma unroll
    for (int k = 0; k < 4; ++k) {
        ushort2 u = h2p[(size_t)a[k] * 64 + lane];
        ushort2 v = h2p[(size_t)b[k] * 64 + lane];
        p[k] = bf2f(u.x) * bf2f(v.x) + bf2f(u.y) * bf2f(v.y);
    }
#pragma unroll
    for (int off = 32; off > 0; off >>= 1) {
#pragma unroll
        for (int k = 0; k < 4; ++k) p[k] += __shfl_down(p[k], off, 64);
    }
    if (lane == 0) {
#pragma unroll
        for (int k = 0; k < 4; ++k) {
            if (l0 + k < L) out[l0 + k] = p[k];
        }
    }
}

// ---------------- host launch ----------------

extern "C" void kernel_launch(void* const* d_in, const int* in_sizes, int n_in,
                              void* d_out, int out_size, void* d_ws, size_t ws_size,
                              hipStream_t stream) {
    const float* x   = (const float*)d_in[0];
    const int*   ei  = (const int*)d_in[1];
    const int*   eli = (const int*)d_in[2];
    const float* W1l = (const float*)d_in[3];
    const float* b1  = (const float*)d_in[4];
    const float* W1r = (const float*)d_in[5];
    const float* W2l = (const float*)d_in[6];
    const float* b2  = (const float*)d_in[7];
    const float* W2r = (const float*)d_in[8];

    const int N = in_sizes[0] / D128;
    const int E = in_sizes[1] / 2;
    const int L = in_sizes[2] / 2;
    const int* srcp = ei;
    const int* dstp = ei + E;
    const int NB = (N + BNODES - 1) >> BSHIFT;   // 196 for N=100000 (<=256)

    char* ws = (char*)d_ws;
    size_t off = 0;
    auto alloc = [&](size_t bytes) -> void* {
        void* p = ws + off;
        off += (bytes + 255) & ~(size_t)255;
        return p;
    };
    const int histBlocks = (E + 8191) / 8192;
    int*   rowptr = (int*)alloc((size_t)(N + 1) * sizeof(int));
    int*   bh     = (int*)alloc((size_t)histBlocks * 256 * sizeof(int));
    int*   bbase  = (int*)alloc(257 * sizeof(int));
    int*   bcur   = (int*)alloc(256 * sizeof(int));
    int*   pairs  = (int*)alloc((size_t)E * sizeof(int));
    int*   srcs   = (int*)alloc(((size_t)E + 16) * sizeof(int));
    unsigned short* xb   = (unsigned short*)alloc((size_t)N * D128 * 2);
    unsigned char*  x8   = (unsigned char*)alloc((size_t)N * D128);
    unsigned char*  h1f8 = (unsigned char*)alloc((size_t)N * D128);
    unsigned short* h1b  = (unsigned short*)alloc((size_t)N * D128 * 2);
    unsigned short* h2b  = (unsigned short*)alloc((size_t)N * D128 * 2);
    unsigned short* Wp   = (unsigned short*)alloc(2 * 32768 * 2);
    (void)ws_size; (void)n_in; (void)out_size;

    // --- 1. fused prep: cast + weight repack + bucket hist partials ---
    int n4 = N * D128 / 4;
    int castBlocks = (n4 + 255) / 256;
    prep_kernel<<<castBlocks + 256 + histBlocks, 256, 0, stream>>>(
        x, xb, x8, n4, W1l, W1r, W2l, W2r, Wp, dstp, bh, E, castBlocks, histBlocks);

    // --- 2-4. CSR build (bucket counting sort) ---
    bucket_scan<<<1, 256, 0, stream>>>(bh, histBlocks, bbase, bcur, rowptr, NB, N, E);
    scatter_kernel<<<(E + 1023) / 1024, 256, 0, stream>>>(srcp, dstp, bcur, pairs, E, NB);
    bucket_fill<<<NB, BNODES, 0, stream>>>(pairs, bbase, rowptr, srcs, N);

    // --- 5. layer 1 (fused agg + GEMM) ---
    int mmBlocks = (N + 63) / 64;
    aggmm_kernel<true><<<mmBlocks, 256, 0, stream>>>(rowptr, srcs, x8, xb, Wp, b1,
                                                     h1b, h1f8, N);

    // --- 6. layer 2 (fused agg + GEMM) ---
    aggmm_kernel<false><<<mmBlocks, 256, 0, stream>>>(rowptr, srcs, h1f8, h1b, Wp + 32768,
                                                      b2, h2b, (unsigned char*)nullptr, N);

    // --- 7. scoring ---
    score_kernel<<<(L + 15) / 16, 256, 0, stream>>>(eli, h2b, (float*)d_out, L);
}

// Round 12
// 445.057 us; speedup vs baseline: 1.0212x; 1.0212x over previous
//
#include <hip/hip_runtime.h>
#include <hip/hip_fp16.h>

// ---------------------------------------------------------------------------
// LinkPredModel: 2-layer GraphSAGE (mean aggr) + dot-product link scoring.
// N=100000 nodes, D=H=128, E=3.2M edges, L=200k label pairs.
// Round 12: aggmm restructured for parallelism — 16 rows/block (grid N/16 =
// 6250), phase 1: 4 waves aggregate 4 rows EACH in parallel; phase 2: each
// wave computes 2 of 8 N-tiles. LDS 4KB with XOR-rotated rows (2-way max
// bank aliasing = free). R11's aggmm was 1563 blocks, 16 serial rows/wave,
// 58% occupancy -> MLP-starved agg phase.
// ---------------------------------------------------------------------------

#define D128 128
#define BSHIFT 9          // 512 nodes per bucket
#define BNODES 512

typedef __bf16 bf16x8 __attribute__((ext_vector_type(8)));
typedef float  f32x4  __attribute__((ext_vector_type(4)));
typedef _Float16 h2   __attribute__((ext_vector_type(2)));

union uh2cast { unsigned u; h2 h; };
__device__ inline h2 uash2(unsigned u) { uh2cast c; c.u = u; return c.h; }
union u4bf8cast { uint4 u; bf16x8 b; };
__device__ inline bf16x8 u4asbf8(uint4 u) { u4bf8cast c; c.u = u; return c.b; }

__device__ inline unsigned short f2bf(float f) {
    unsigned u = __float_as_uint(f);
    u = u + 0x7FFF + ((u >> 16) & 1);   // round-to-nearest-even
    return (unsigned short)(u >> 16);
}
__device__ inline float bf2f(unsigned short s) {
    return __uint_as_float(((unsigned)s) << 16);
}
__device__ inline unsigned packbf2(float lo, float hi) {
    return (unsigned)f2bf(lo) | ((unsigned)f2bf(hi) << 16);
}
// fp8 e5m2 encode. HW packer when available (1 VALU), else fp16 double-round.
__device__ inline unsigned char f2e5(float f) {
#if __has_builtin(__builtin_amdgcn_cvt_pk_bf8_f32)
    return (unsigned char)(__builtin_amdgcn_cvt_pk_bf8_f32(f, f, 0, false) & 0xFF);
#else
    unsigned short h = __half_as_ushort(__float2half(f));  // RNE f32->fp16
    h = (unsigned short)(h + 0x7F + ((h >> 8) & 1));       // RNE fp16->e5m2
    return (unsigned char)(h >> 8);
#endif
}

// ---------------- fused prep: cast | weight repack | bucket hist partials ----

__global__ void prep_kernel(const float* __restrict__ in, unsigned short* __restrict__ outb,
                            unsigned char* __restrict__ out8, int n4,
                            const float* __restrict__ W1l, const float* __restrict__ W1r,
                            const float* __restrict__ W2l, const float* __restrict__ W2r,
                            unsigned short* __restrict__ packed,
                            const int* __restrict__ dst, int* __restrict__ bh,
                            int E, int castBlocks, int histBlocks) {
    int bid = blockIdx.x;
    int t = threadIdx.x;
    if (bid < castBlocks) {
        int i = bid * 256 + t;
        if (i >= n4) return;
        float4 v = ((const float4*)in)[i];
        ushort4 ob;
        ob.x = f2bf(v.x); ob.y = f2bf(v.y); ob.z = f2bf(v.z); ob.w = f2bf(v.w);
        ((ushort4*)outb)[i] = ob;
        unsigned p = (unsigned)f2e5(v.x) | ((unsigned)f2e5(v.y) << 8) |
                     ((unsigned)f2e5(v.z) << 16) | ((unsigned)f2e5(v.w) << 24);
        ((unsigned*)out8)[i] = p;
    } else if (bid < castBlocks + 256) {
        // weight repack: packed[layer][kc][nt][lane][j] = W[k][col],
        // k=kc*32+(lane>>4)*8+j, col=nt*16+(lane&15); k<128 -> Wl else Wr.
        int tid = (bid - castBlocks) * 256 + t;  // [0, 65536)
        int layer = tid >> 15;
        int r = tid & 32767;
        int j    = r & 7;
        int lane = (r >> 3) & 63;
        int nt   = (r >> 9) & 7;
        int kc   = (r >> 12) & 7;
        int k   = kc * 32 + ((lane >> 4) << 3) + j;
        int col = nt * 16 + (lane & 15);
        const float* Wl = layer ? W2l : W1l;
        const float* Wr = layer ? W2r : W1r;
        float v = (k < 128) ? Wl[k * 128 + col] : Wr[(k - 128) * 128 + col];
        packed[tid] = f2bf(v);
    } else {
        // bucket histogram partials (plain stores, no memset/global atomics)
        __shared__ int h[256];
        int hb = bid - castBlocks - 256;
        if (hb >= histBlocks) return;
        h[t] = 0;
        __syncthreads();
        int base = hb * 8192;
#pragma unroll
        for (int k = 0; k < 32; ++k) {
            int e = base + k * 256 + t;
            if (e < E) atomicAdd(&h[dst[e] >> BSHIFT], 1);
        }
        __syncthreads();
        bh[hb * 256 + t] = h[t];
    }
}

// ---------------- bucket scan: ILP-parallel partial-sum + exclusive scan ------

__global__ void bucket_scan(const int* __restrict__ bh, int nhb,
                            int* __restrict__ bucket_base, int* __restrict__ bucket_cur,
                            int* __restrict__ rowptr, int NB, int N, int E) {
    __shared__ int sc[256];
    __shared__ int orig[256];
    int t = threadIdx.x;
    int a0 = 0, a1 = 0, a2 = 0, a3 = 0, a4 = 0, a5 = 0, a6 = 0, a7 = 0;
    int b = 0;
    for (; b + 8 <= nhb; b += 8) {
        a0 += bh[(b + 0) * 256 + t];
        a1 += bh[(b + 1) * 256 + t];
        a2 += bh[(b + 2) * 256 + t];
        a3 += bh[(b + 3) * 256 + t];
        a4 += bh[(b + 4) * 256 + t];
        a5 += bh[(b + 5) * 256 + t];
        a6 += bh[(b + 6) * 256 + t];
        a7 += bh[(b + 7) * 256 + t];
    }
    for (; b < nhb; ++b) a0 += bh[b * 256 + t];
    int v = ((a0 + a1) + (a2 + a3)) + ((a4 + a5) + (a6 + a7));
    if (t >= NB) v = 0;
    orig[t] = v;
    sc[t] = v;
    __syncthreads();
    for (int off = 1; off < 256; off <<= 1) {
        int a = (t >= off) ? sc[t - off] : 0;
        __syncthreads();
        sc[t] += a;
        __syncthreads();
    }
    int ex = sc[t] - orig[t];
    if (t < NB) { bucket_base[t] = ex; bucket_cur[t] = ex; }
    if (t == 0) { bucket_base[NB] = E; rowptr[N] = E; }
}

// packed edge word: (src << 9) | (dst & 511); src < 2^17, so fits in 26 bits.
__global__ void scatter_kernel(const int* __restrict__ src, const int* __restrict__ dst,
                               int* __restrict__ bucket_cur, int* __restrict__ pairs,
                               int E, int NB) {
    __shared__ int hist[256], lscan[256], gbase[256];
    __shared__ int lsrc[1024], ldst[1024];
    int t = threadIdx.x;
    hist[t] = 0;
    __syncthreads();
    int base = blockIdx.x * 1024;
    int total = E - base; if (total > 1024) total = 1024;

    int ms[4], md[4], mb[4], mr[4];
#pragma unroll
    for (int k = 0; k < 4; ++k) {
        int i = k * 256 + t;
        int e = base + i;
        mb[k] = -1;
        if (i < total) {
            ms[k] = src[e];
            md[k] = dst[e];
            mb[k] = md[k] >> BSHIFT;
            mr[k] = atomicAdd(&hist[mb[k]], 1);
        }
    }
    __syncthreads();
    lscan[t] = hist[t];
    __syncthreads();
    for (int off = 1; off < 256; off <<= 1) {
        int a = (t >= off) ? lscan[t - off] : 0;
        __syncthreads();
        lscan[t] += a;
        __syncthreads();
    }
    lscan[t] -= hist[t];
    if (t < NB && hist[t] > 0) gbase[t] = atomicAdd(&bucket_cur[t], hist[t]);
    __syncthreads();
#pragma unroll
    for (int k = 0; k < 4; ++k) {
        if (mb[k] >= 0) {
            int idx = lscan[mb[k]] + mr[k];
            lsrc[idx] = ms[k];
            ldst[idx] = md[k];
        }
    }
    __syncthreads();
#pragma unroll
    for (int k = 0; k < 4; ++k) {
        int i = k * 256 + t;
        if (i < total) {
            int d = ldst[i];
            int b = d >> BSHIFT;
            int pos = gbase[b] + (i - lscan[b]);
            pairs[pos] = (lsrc[i] << BSHIFT) | (d & (BNODES - 1));
        }
    }
}

// srcs stores PRE-SCALED row index: src*16 (uint2 units for a 128B fp8 row).
__global__ void bucket_fill(const int* __restrict__ pairs, const int* __restrict__ bucket_base,
                            int* __restrict__ rowptr, int* __restrict__ srcs, int N) {
    __shared__ int hist[BNODES], excl[BNODES], sc[BNODES];
    int b = blockIdx.x;
    int t = threadIdx.x;      // blockDim = 512
    int node0 = b << BSHIFT;
    int pbeg = bucket_base[b];
    int pend = bucket_base[b + 1];
    hist[t] = 0;
    __syncthreads();
    for (int p = pbeg + t; p < pend; p += BNODES) {
        atomicAdd(&hist[pairs[p] & (BNODES - 1)], 1);
    }
    __syncthreads();
    sc[t] = hist[t];
    __syncthreads();
    for (int off = 1; off < BNODES; off <<= 1) {
        int a = (t >= off) ? sc[t - off] : 0;
        __syncthreads();
        sc[t] += a;
        __syncthreads();
    }
    excl[t] = sc[t] - hist[t];
    int node = node0 + t;
    if (node < N) rowptr[node] = pbeg + excl[t];
    __syncthreads();
    hist[t] = 0;
    __syncthreads();
    for (int p = pbeg + t; p < pend; p += BNODES) {
        int w = pairs[p];
        int dl = w & (BNODES - 1);
        int c = atomicAdd(&hist[dl], 1);
        srcs[pbeg + excl[dl] + c] = (int)(((unsigned)w) >> BSHIFT) << 4;
    }
}

// ---------------- fused agg + MFMA dual-GEMM (one layer) ----------------
// 16 rows per block (grid N/16). Phase 1: wave w aggregates rows m0+w*4..+3
// in PARALLEL across waves (R10 inner loop: fp8 gather, pk_add_f16) into
// 4KB LDS (bf16, XOR-rotated rows: uint4 col (c+row)&15 => <=2-way banks).
// Phase 2: wave w computes N-tiles nt = 2w, 2w+1 of out = act([agg|F]@Wp+b),
// A-frags from LDS, F rows + W from global.

__device__ inline void pkacc8(h2* A, uint2 v) {
    A[0] += uash2((v.x << 8) & 0xFF00FF00u);   // cols 0,2
    A[1] += uash2(v.x & 0xFF00FF00u);          // cols 1,3
    A[2] += uash2((v.y << 8) & 0xFF00FF00u);   // cols 4,6
    A[3] += uash2(v.y & 0xFF00FF00u);          // cols 5,7
}

template <bool LEAKY>
__global__ void aggmm_kernel(const int* __restrict__ rowptr, const int* __restrict__ srcs,
                             const unsigned char* __restrict__ feat8,
                             const unsigned short* __restrict__ F,
                             const unsigned short* __restrict__ Wp,
                             const float* __restrict__ bias,
                             unsigned short* __restrict__ out,
                             unsigned char* __restrict__ out8, int N) {
    __shared__ unsigned short ldsA[16 * D128];   // 4 KB, rows XOR-rotated
    int wid = threadIdx.x >> 6;
    int lane = threadIdx.x & 63;
    int q  = lane >> 4;    // quarter
    int ql = lane & 15;
    int m0 = blockIdx.x * 16;
    const uint2* f = (const uint2*)feat8;   // 16 uint2 per 128B fp8 row

    // ---- phase 1: wave wid aggregates rows m0+wid*4 .. +3 (parallel) ----
#pragma unroll
    for (int i = 0; i < 4; ++i) {
        int rloc = wid * 4 + i;
        int n = m0 + rloc;
        if (n < N) {
            int beg = rowptr[n];
            int end = rowptr[n + 1];

            h2 A0[4], A1[4], A2[4], A3[4];
            h2 z; z[0] = (_Float16)0.f; z[1] = (_Float16)0.f;
#pragma unroll
            for (int k = 0; k < 4; ++k) { A0[k] = z; A1[k] = z; A2[k] = z; A3[k] = z; }

            int j = beg;
            for (; j + 16 <= end; j += 16) {
                int e0 = srcs[j + q];
                int e1 = srcs[j + 4 + q];
                int e2 = srcs[j + 8 + q];
                int e3 = srcs[j + 12 + q];
                uint2 v0 = f[e0 + ql];
                uint2 v1 = f[e1 + ql];
                uint2 v2 = f[e2 + ql];
                uint2 v3 = f[e3 + ql];
                pkacc8(A0, v0);
                pkacc8(A1, v1);
                pkacc8(A2, v2);
                pkacc8(A3, v3);
            }
            for (; j + 4 <= end; j += 4) {
                uint2 v = f[srcs[j + q] + ql];
                pkacc8(A0, v);
            }
            int rem = end - j;
            if (q < rem) {
                uint2 v = f[srcs[j + q] + ql];
                pkacc8(A1, v);
            }

            float c[8];
#pragma unroll
            for (int p = 0; p < 4; ++p) {
                float lo = (float)A0[p][0] + (float)A1[p][0] + (float)A2[p][0] + (float)A3[p][0];
                float hi = (float)A0[p][1] + (float)A1[p][1] + (float)A2[p][1] + (float)A3[p][1];
                int base = (p >> 1) * 4 + (p & 1);
                c[base] = lo;
                c[base + 2] = hi;
            }
#pragma unroll
            for (int k = 0; k < 8; ++k) {
                c[k] += __shfl_xor(c[k], 16, 64);
                c[k] += __shfl_xor(c[k], 32, 64);
            }
            int deg = end - beg;
            float inv = deg > 0 ? 1.0f / (float)deg : 0.f;
            if (q == 0) {
                uint4 rr;
                rr.x = packbf2(c[0] * inv, c[1] * inv);
                rr.y = packbf2(c[2] * inv, c[3] * inv);
                rr.z = packbf2(c[4] * inv, c[5] * inv);
                rr.w = packbf2(c[6] * inv, c[7] * inv);
                ((uint4*)ldsA)[rloc * 16 + ((ql + rloc) & 15)] = rr;  // rotated
            }
        }
    }
    __syncthreads();

    // ---- phase 2: wave wid computes N-tiles nt = 2*wid, 2*wid+1 ----
    int rl = lane & 15;
    int rowF = m0 + rl;
    if (rowF > N - 1) rowF = N - 1;
    int nt0 = wid * 2;

    f32x4 acc[2];
    acc[0] = (f32x4){0.f, 0.f, 0.f, 0.f};
    acc[1] = (f32x4){0.f, 0.f, 0.f, 0.f};

#pragma unroll
    for (int kc = 0; kc < 8; ++kc) {
        bf16x8 af;
        if (kc < 4) {
            uint4 u = ((const uint4*)ldsA)[rl * 16 + ((kc * 4 + q + rl) & 15)];
            af = u4asbf8(u);
        } else {
            af = *(const bf16x8*)(F + (size_t)rowF * D128 + (kc - 4) * 32 + q * 8);
        }
        const unsigned short* wp = Wp + ((size_t)kc * 8) * 512 + lane * 8;
        bf16x8 bf0 = *(const bf16x8*)(wp + nt0 * 512);
        bf16x8 bf1 = *(const bf16x8*)(wp + (nt0 + 1) * 512);
        acc[0] = __builtin_amdgcn_mfma_f32_16x16x32_bf16(af, bf0, acc[0], 0, 0, 0);
        acc[1] = __builtin_amdgcn_mfma_f32_16x16x32_bf16(af, bf1, acc[1], 0, 0, 0);
    }

#pragma unroll
    for (int t = 0; t < 2; ++t) {
        int col = (nt0 + t) * 16 + rl;
        float bv = bias[col];
#pragma unroll
        for (int r = 0; r < 4; ++r) {
            int row = m0 + q * 4 + r;
            if (row < N) {
                float v = acc[t][r] + bv;
                if (LEAKY) v = v >= 0.f ? v : 0.2f * v;
                out[(size_t)row * D128 + col] = f2bf(v);
                if (out8) out8[(size_t)row * D128 + col] = f2e5(v);
            }
        }
    }
}

// ---------------- link scoring: 4 pairs per wave (8 gathers in flight) ----------------

__global__ void score_kernel(const int* __restrict__ eli, const unsigned short* __restrict__ h,
                             float* __restrict__ out, int L) {
    int wave = threadIdx.x >> 6;
    int lane = threadIdx.x & 63;
    int l0 = (blockIdx.x * 4 + wave) * 4;
    if (l0 >= L) return;
    const ushort2* h2p = (const ushort2*)h;
    int a[4], b[4];
#pragma unroll
    for (int k = 0; k < 4; ++k) {
        int l = l0 + k;
        if (l > L - 1) l = L - 1;
        a[k] = eli[l];
        b[k] = eli[L + l];
    }
    float p[4];
#pragma unroll
    for (int k = 0; k < 4; ++k) {
        ushort2 u = h2p[(size_t)a[k] * 64 + lane];
        ushort2 v = h2p[(size_t)b[k] * 64 + lane];
        p[k] = bf2f(u.x) * bf2f(v.x) + bf2f(u.y) * bf2f(v.y);
    }
#pragma unroll
    for (int off = 32; off > 0; off >>= 1) {
#pragma unroll
        for (int k = 0; k < 4; ++k) p[k] += __shfl_down(p[k], off, 64);
    }
    if (lane == 0) {
#pragma unroll
        for (int k = 0; k < 4; ++k) {
            if (l0 + k < L) out[l0 + k] = p[k];
        }
    }
}

// ---------------- host launch ----------------

extern "C" void kernel_launch(void* const* d_in, const int* in_sizes, int n_in,
                              void* d_out, int out_size, void* d_ws, size_t ws_size,
                              hipStream_t stream) {
    const float* x   = (const float*)d_in[0];
    const int*   ei  = (const int*)d_in[1];
    const int*   eli = (const int*)d_in[2];
    const float* W1l = (const float*)d_in[3];
    const float* b1  = (const float*)d_in[4];
    const float* W1r = (const float*)d_in[5];
    const float* W2l = (const float*)d_in[6];
    const float* b2  = (const float*)d_in[7];
    const float* W2r = (const float*)d_in[8];

    const int N = in_sizes[0] / D128;
    const int E = in_sizes[1] / 2;
    const int L = in_sizes[2] / 2;
    const int* srcp = ei;
    const int* dstp = ei + E;
    const int NB = (N + BNODES - 1) >> BSHIFT;   // 196 for N=100000 (<=256)

    char* ws = (char*)d_ws;
    size_t off = 0;
    auto alloc = [&](size_t bytes) -> void* {
        void* p = ws + off;
        off += (bytes + 255) & ~(size_t)255;
        return p;
    };
    const int histBlocks = (E + 8191) / 8192;
    int*   rowptr = (int*)alloc((size_t)(N + 1) * sizeof(int));
    int*   bh     = (int*)alloc((size_t)histBlocks * 256 * sizeof(int));
    int*   bbase  = (int*)alloc(257 * sizeof(int));
    int*   bcur   = (int*)alloc(256 * sizeof(int));
    int*   pairs  = (int*)alloc((size_t)E * sizeof(int));
    int*   srcs   = (int*)alloc(((size_t)E + 16) * sizeof(int));
    unsigned short* xb   = (unsigned short*)alloc((size_t)N * D128 * 2);
    unsigned char*  x8   = (unsigned char*)alloc((size_t)N * D128);
    unsigned char*  h1f8 = (unsigned char*)alloc((size_t)N * D128);
    unsigned short* h1b  = (unsigned short*)alloc((size_t)N * D128 * 2);
    unsigned short* h2b  = (unsigned short*)alloc((size_t)N * D128 * 2);
    unsigned short* Wp   = (unsigned short*)alloc(2 * 32768 * 2);
    (void)ws_size; (void)n_in; (void)out_size;

    // --- 1. fused prep: cast + weight repack + bucket hist partials ---
    int n4 = N * D128 / 4;
    int castBlocks = (n4 + 255) / 256;
    prep_kernel<<<castBlocks + 256 + histBlocks, 256, 0, stream>>>(
        x, xb, x8, n4, W1l, W1r, W2l, W2r, Wp, dstp, bh, E, castBlocks, histBlocks);

    // --- 2-4. CSR build (bucket counting sort) ---
    bucket_scan<<<1, 256, 0, stream>>>(bh, histBlocks, bbase, bcur, rowptr, NB, N, E);
    scatter_kernel<<<(E + 1023) / 1024, 256, 0, stream>>>(srcp, dstp, bcur, pairs, E, NB);
    bucket_fill<<<NB, BNODES, 0, stream>>>(pairs, bbase, rowptr, srcs, N);

    // --- 5. layer 1 (fused agg + GEMM) ---
    int mmBlocks = (N + 15) / 16;
    aggmm_kernel<true><<<mmBlocks, 256, 0, stream>>>(rowptr, srcs, x8, xb, Wp, b1,
                                                     h1b, h1f8, N);

    // --- 6. layer 2 (fused agg + GEMM) ---
    aggmm_kernel<false><<<mmBlocks, 256, 0, stream>>>(rowptr, srcs, h1f8, h1b, Wp + 32768,
                                                      b2, h2b, (unsigned char*)nullptr, N);

    // --- 7. scoring ---
    score_kernel<<<(L + 15) / 16, 256, 0, stream>>>(eli, h2b, (float*)d_out, L);
}